// Round 1
// baseline (643.159 us; speedup 1.0000x reference)
//
#include <hip/hip_runtime.h>
#include <math.h>

#define NPTS   131072
#define NB     32
#define HD     64
#define LIMIT  10.0f
#define CLAMPV 10000.0f

__global__ void zero_out_kernel(float* out) {
    out[0] = 0.0f;
}

__global__ __launch_bounds__(256) void realnvp_kernel(
    const float* __restrict__ x,
    const float* __restrict__ W1, const float* __restrict__ b1,
    const float* __restrict__ W2, const float* __restrict__ b2,
    const float* __restrict__ W3, const float* __restrict__ b3,
    const float* __restrict__ loc, const float* __restrict__ log_scale,
    float* __restrict__ out)
{
    __shared__ float W2s[HD * HD];      // 16 KB, current block's 64x64
    __shared__ float w1s[HD], b1s[HD], b2s[HD];
    __shared__ float w3s[2 * HD];
    __shared__ float b3s[2];
    __shared__ float red[4];

    const int tid = threadIdx.x;
    const int gid = blockIdx.x * 256 + tid;

    float za = x[2 * gid + 0];
    float zb = x[2 * gid + 1];
    float ld = 0.0f;
    bool mask = true;

    for (int t = 0; t < NB; ++t) {
        const int p = NB - 1 - t;   // params are reversed in the scan

        __syncthreads();            // protect prior iteration's LDS reads
        {
            const float* W2p = W2 + p * HD * HD;
            #pragma unroll
            for (int i = 0; i < (HD * HD) / 256; ++i)
                W2s[tid + 256 * i] = W2p[tid + 256 * i];
            if (tid < HD) {
                w1s[tid] = W1[p * HD + tid];
                b1s[tid] = b1[p * HD + tid];
                b2s[tid] = b2[p * HD + tid];
            }
            if (tid < 2 * HD) w3s[tid] = W3[p * 2 * HD + tid];
            if (tid < 2)      b3s[tid] = b3[p * 2 + tid];
        }
        __syncthreads();

        // --- permute step: z_out = clip(swap(z)); mask &= |z|<R (pre-permute z)
        bool in1 = (fabsf(za) < LIMIT) && (fabsf(zb) < LIMIT);
        mask = mask && in1;
        if (mask) {
            float na = fminf(fmaxf(zb, -CLAMPV), CLAMPV);
            float nb = fminf(fmaxf(za, -CLAMPV), CLAMPV);
            za = na; zb = nb;
        }

        // --- coupling inverse: MLP(z1) -> (shift, scale)
        const float z1 = za, z2 = zb;

        float h2[HD];
        #pragma unroll
        for (int j = 0; j < HD; ++j) h2[j] = b2s[j];

        for (int k = 0; k < HD; ++k) {
            float h1k = fmaxf(fmaf(z1, w1s[k], b1s[k]), 0.0f);
            const float4* row = (const float4*)(&W2s[k * HD]);
            #pragma unroll
            for (int j4 = 0; j4 < HD / 4; ++j4) {
                float4 w = row[j4];   // wave-uniform address -> LDS broadcast
                h2[4 * j4 + 0] = fmaf(h1k, w.x, h2[4 * j4 + 0]);
                h2[4 * j4 + 1] = fmaf(h1k, w.y, h2[4 * j4 + 1]);
                h2[4 * j4 + 2] = fmaf(h1k, w.z, h2[4 * j4 + 2]);
                h2[4 * j4 + 3] = fmaf(h1k, w.w, h2[4 * j4 + 3]);
            }
        }

        float shift = b3s[0], scale = b3s[1];
        #pragma unroll
        for (int j = 0; j < HD; ++j) {
            float hj = fmaxf(h2[j], 0.0f);   // relu of layer 2
            shift = fmaf(hj, w3s[2 * j + 0], shift);
            scale = fmaf(hj, w3s[2 * j + 1], scale);
        }

        float z2n = (z2 - shift) * __expf(-scale);

        // --- second mask check on post-permute z, then gated update
        bool in2 = (fabsf(za) < LIMIT) && (fabsf(zb) < LIMIT);
        mask = mask && in2;
        if (mask) {
            za = fminf(fmaxf(z1, -CLAMPV), CLAMPV);
            zb = fminf(fmaxf(z2n, -CLAMPV), CLAMPV);
            ld -= scale;
        }
    }

    // --- base log-prob
    const float l0 = loc[0], l1 = loc[1];
    const float ls0 = log_scale[0], ls1 = log_scale[1];
    const float e0 = __expf(-ls0), e1 = __expf(-ls1);
    const float t0 = (za - l0) * e0, t1 = (zb - l1) * e1;
    // -0.5*D*log(2*pi) with D=2
    float val = -1.8378770664093453f - (ls0 + ls1)
                - 0.5f * (t0 * t0 + t1 * t1) + ld;

    // --- reduction: wave shuffle -> LDS -> one atomic per workgroup
    #pragma unroll
    for (int off = 32; off > 0; off >>= 1)
        val += __shfl_down(val, off, 64);

    const int wave = tid >> 6;
    if ((tid & 63) == 0) red[wave] = val;
    __syncthreads();
    if (tid == 0) {
        float s = red[0] + red[1] + red[2] + red[3];
        atomicAdd(out, s);
    }
}

extern "C" void kernel_launch(void* const* d_in, const int* in_sizes, int n_in,
                              void* d_out, int out_size, void* d_ws, size_t ws_size,
                              hipStream_t stream) {
    const float* x   = (const float*)d_in[0];
    const float* W1  = (const float*)d_in[1];
    const float* b1  = (const float*)d_in[2];
    const float* W2  = (const float*)d_in[3];
    const float* b2  = (const float*)d_in[4];
    const float* W3  = (const float*)d_in[5];
    const float* b3  = (const float*)d_in[6];
    const float* loc = (const float*)d_in[7];
    const float* lsc = (const float*)d_in[8];
    float* out = (float*)d_out;

    zero_out_kernel<<<1, 1, 0, stream>>>(out);
    realnvp_kernel<<<NPTS / 256, 256, 0, stream>>>(
        x, W1, b1, W2, b2, W3, b3, loc, lsc, out);
}